// Round 2
// baseline (1000.054 us; speedup 1.0000x reference)
//
#include <hip/hip_runtime.h>
#include <hip/hip_bf16.h>

// Problem: S=1024, B=64, QK=H=DV=1024.
// Fused: score[r]=sum_h wv[h]*tanh( (Q@Wq^T + K@Wk^T)[r,h] ), r=s*64+b
//        attn = softmax_s(score); out[b,d] = sum_s attn[s,b]*V[s,d]
// Single GEMM view: A'[65536x2048] (Q||K rows) x B'[1024x2048] (Wq||Wk rows).

#define S_DIM 1024
#define B_DIM 64
#define R_DIM 65536   // S*B
#define H_DIM 1024
#define KP    2048    // fused K' = 2*1024
#define DV    1024

typedef __attribute__((ext_vector_type(8))) short bf16x8;
typedef __attribute__((ext_vector_type(4))) float f32x4;

__device__ __forceinline__ unsigned short f2bf(float x) {
    __hip_bfloat16 h = __float2bfloat16(x);   // RNE
    return *reinterpret_cast<unsigned short*>(&h);
}

__device__ __forceinline__ float fast_tanh(float x) {
    // tanh(x) = 1 - 2/(exp(2x)+1); exp overflow -> inf -> 1, underflow -> -1. Correct limits.
    float e = __expf(2.0f * x);
    return 1.0f - 2.0f / (e + 1.0f);
}

// ---- prepass: fp32 -> bf16, fused-K layout  A[r*2048 + (0..1023 Q | 1024..2047 K)] ----
__global__ void cvt_qk_kernel(const float* __restrict__ q, const float* __restrict__ k,
                              unsigned short* __restrict__ A) {
    size_t t = (size_t)blockIdx.x * blockDim.x + threadIdx.x;  // float4 index < 16777216
    size_t e = t * 4;
    size_t r = e >> 10;
    size_t c = e & 1023;
    float4 vq = reinterpret_cast<const float4*>(q)[t];
    float4 vk = reinterpret_cast<const float4*>(k)[t];
    ushort4 uq = { f2bf(vq.x), f2bf(vq.y), f2bf(vq.z), f2bf(vq.w) };
    ushort4 uk = { f2bf(vk.x), f2bf(vk.y), f2bf(vk.z), f2bf(vk.w) };
    *reinterpret_cast<ushort4*>(&A[r * KP + c])        = uq;
    *reinterpret_cast<ushort4*>(&A[r * KP + 1024 + c]) = uk;
}

__global__ void cvt_w_kernel(const float* __restrict__ wq, const float* __restrict__ wk,
                             unsigned short* __restrict__ Bm) {
    size_t t = (size_t)blockIdx.x * blockDim.x + threadIdx.x;  // float4 index < 262144
    size_t e = t * 4;
    size_t h = e >> 10;
    size_t c = e & 1023;
    float4 vq = reinterpret_cast<const float4*>(wq)[t];
    float4 vk = reinterpret_cast<const float4*>(wk)[t];
    ushort4 uq = { f2bf(vq.x), f2bf(vq.y), f2bf(vq.z), f2bf(vq.w) };
    ushort4 uk = { f2bf(vk.x), f2bf(vk.y), f2bf(vk.z), f2bf(vk.w) };
    *reinterpret_cast<ushort4*>(&Bm[h * KP + c])        = uq;
    *reinterpret_cast<ushort4*>(&Bm[h * KP + 1024 + c]) = uk;
}

// ---- main fused GEMM + tanh/wv epilogue -> partial scores via atomicAdd ----
// Block: 256 thr (4 waves, 2x2), tile 128(M) x 128(N), BK=32 over K'=2048 (64 iters).
// LDS rows padded 32->40 elems: b128 frag reads hit each bank at most 2x (free).
// PRE staging: 2 thr/row, each thread loads 32 B (two dwordx4) = 16 ushorts.
template<bool PRE>
__global__ __launch_bounds__(256, 2)
void score_gemm(const float* __restrict__ q, const float* __restrict__ kmat,
                const float* __restrict__ wqm, const float* __restrict__ wkm,
                const unsigned short* __restrict__ Abf, const unsigned short* __restrict__ Bbf,
                const float* __restrict__ wv, float* __restrict__ scores) {
    __shared__ unsigned short As[128][40];
    __shared__ unsigned short Bs[128][40];
    __shared__ float wvs[128];

    const int tid = threadIdx.x;
    const int bm = blockIdx.x >> 3;   // 512 M tiles
    const int bn = blockIdx.x & 7;    // 8 N tiles (consecutive -> A tile stays hot in LLC)

    if (tid < 128) wvs[tid] = wv[bn * 128 + tid];

    const int lane = tid & 63;
    const int w  = tid >> 6;
    const int wm = w >> 1, wn = w & 1;          // 2x2 wave grid, 64x64 per wave
    const int l15 = lane & 15;
    const int lk  = (lane >> 4) * 8;            // frag k-offset (elems)

    f32x4 acc[4][4];
#pragma unroll
    for (int mi = 0; mi < 4; ++mi)
#pragma unroll
        for (int ni = 0; ni < 4; ++ni) acc[mi][ni] = (f32x4){0.f, 0.f, 0.f, 0.f};

    // staging state (unused set is dead-code eliminated by if constexpr)
    uint4 ra0, ra1, rb0, rb1;
    float4 fa[4], fb[4];

    const int prow = tid >> 1;            // PRE: 128 rows, 2 thr/row
    const int pkh  = (tid & 1) * 16;      // PRE: 16-elem (32 B) half-row
    const int rrow = tid >> 3;            // !PRE: 32 rows/pass
    const int rcol = (tid & 7) * 4;       // !PRE: float4 column

    const unsigned short* pa = PRE ? (Abf + (size_t)(bm * 128 + prow) * KP + pkh) : nullptr;
    const unsigned short* pb = PRE ? (Bbf + (size_t)(bn * 128 + prow) * KP + pkh) : nullptr;

    auto prefetch = [&](int kc) {
        if constexpr (PRE) {
            ra0 = *reinterpret_cast<const uint4*>(pa + kc * 32);
            ra1 = *reinterpret_cast<const uint4*>(pa + kc * 32 + 8);
            rb0 = *reinterpret_cast<const uint4*>(pb + kc * 32);
            rb1 = *reinterpret_cast<const uint4*>(pb + kc * 32 + 8);
        } else {
            const float* ap = (kc < 32) ? q   : kmat;
            const float* bp = (kc < 32) ? wqm : wkm;
            const int kb = (kc & 31) * 32 + rcol;
#pragma unroll
            for (int p4 = 0; p4 < 4; ++p4) {
                fa[p4] = *reinterpret_cast<const float4*>(&ap[(size_t)(bm * 128 + p4 * 32 + rrow) * 1024 + kb]);
                fb[p4] = *reinterpret_cast<const float4*>(&bp[(size_t)(bn * 128 + p4 * 32 + rrow) * 1024 + kb]);
            }
        }
    };

    prefetch(0);

    for (int kc = 0; kc < 64; ++kc) {
        __syncthreads();   // previous iter's frag reads complete
        if constexpr (PRE) {
            *reinterpret_cast<uint4*>(&As[prow][pkh])     = ra0;
            *reinterpret_cast<uint4*>(&As[prow][pkh + 8]) = ra1;
            *reinterpret_cast<uint4*>(&Bs[prow][pkh])     = rb0;
            *reinterpret_cast<uint4*>(&Bs[prow][pkh + 8]) = rb1;
        } else {
#pragma unroll
            for (int p4 = 0; p4 < 4; ++p4) {
                ushort4 ua = { f2bf(fa[p4].x), f2bf(fa[p4].y), f2bf(fa[p4].z), f2bf(fa[p4].w) };
                ushort4 ub = { f2bf(fb[p4].x), f2bf(fb[p4].y), f2bf(fb[p4].z), f2bf(fb[p4].w) };
                *reinterpret_cast<ushort4*>(&As[p4 * 32 + rrow][rcol]) = ua;
                *reinterpret_cast<ushort4*>(&Bs[p4 * 32 + rrow][rcol]) = ub;
            }
        }
        __syncthreads();   // LDS ready
        if (kc + 1 < 64) prefetch(kc + 1);   // overlap next global load with MFMA

        bf16x8 af[4], bfr[4];
#pragma unroll
        for (int mi = 0; mi < 4; ++mi)
            af[mi] = *reinterpret_cast<const bf16x8*>(&As[wm * 64 + mi * 16 + l15][lk]);
#pragma unroll
        for (int ni = 0; ni < 4; ++ni)
            bfr[ni] = *reinterpret_cast<const bf16x8*>(&Bs[wn * 64 + ni * 16 + l15][lk]);
#pragma unroll
        for (int mi = 0; mi < 4; ++mi)
#pragma unroll
            for (int ni = 0; ni < 4; ++ni)
                acc[mi][ni] = __builtin_amdgcn_mfma_f32_16x16x32_bf16(af[mi], bfr[ni], acc[mi][ni], 0, 0, 0);
    }

    // epilogue: p[row] = sum over this block's 128 h of wv[h]*tanh(C[row,h])
    // C/D layout (verified m89/m91): col = lane&15, row = (lane>>4)*4 + reg
    float wvv[4];
#pragma unroll
    for (int ni = 0; ni < 4; ++ni) wvv[ni] = wvs[wn * 64 + ni * 16 + l15];

    float p[4][4];
#pragma unroll
    for (int mi = 0; mi < 4; ++mi)
#pragma unroll
        for (int r = 0; r < 4; ++r) {
            float s = 0.f;
#pragma unroll
            for (int ni = 0; ni < 4; ++ni) s += wvv[ni] * fast_tanh(acc[mi][ni][r]);
            // butterfly over the 16 col-lanes holding the same row
            s += __shfl_xor(s, 1);
            s += __shfl_xor(s, 2);
            s += __shfl_xor(s, 4);
            s += __shfl_xor(s, 8);
            p[mi][r] = s;
        }

    if (l15 == 0) {
        const int rbase = bm * 128 + wm * 64 + (lane >> 4) * 4;
#pragma unroll
        for (int mi = 0; mi < 4; ++mi)
#pragma unroll
            for (int r = 0; r < 4; ++r)
                atomicAdd(&scores[rbase + mi * 16 + r], p[mi][r]);
    }
}

// ---- softmax over s (axis 0) per b; scores[s*64+b] -> attn[s*64+b] ----
__global__ void softmax_kernel(const float* __restrict__ scores, float* __restrict__ attn) {
    const int b = blockIdx.x;       // 64 blocks
    const int t = threadIdx.x;      // 256 threads, 4 s each
    __shared__ float red[4];
    __shared__ float red2[4];

    float v0 = scores[(t +   0) * 64 + b];
    float v1 = scores[(t + 256) * 64 + b];
    float v2 = scores[(t + 512) * 64 + b];
    float v3 = scores[(t + 768) * 64 + b];

    float m = fmaxf(fmaxf(v0, v1), fmaxf(v2, v3));
#pragma unroll
    for (int off = 1; off < 64; off <<= 1) m = fmaxf(m, __shfl_xor(m, off));
    if ((t & 63) == 0) red[t >> 6] = m;
    __syncthreads();
    m = fmaxf(fmaxf(red[0], red[1]), fmaxf(red[2], red[3]));

    float e0 = __expf(v0 - m), e1 = __expf(v1 - m), e2 = __expf(v2 - m), e3 = __expf(v3 - m);
    float s = e0 + e1 + e2 + e3;
#pragma unroll
    for (int off = 1; off < 64; off <<= 1) s += __shfl_xor(s, off);
    if ((t & 63) == 0) red2[t >> 6] = s;
    __syncthreads();
    s = red2[0] + red2[1] + red2[2] + red2[3];

    float inv = 1.0f / s;
    attn[(t +   0) * 64 + b] = e0 * inv;
    attn[(t + 256) * 64 + b] = e1 * inv;
    attn[(t + 512) * 64 + b] = e2 * inv;
    attn[(t + 768) * 64 + b] = e3 * inv;
}

// ---- out[b,d] = sum_s attn[s,b] * V[s,d] ----
__global__ void out_kernel(const float* __restrict__ attn, const float* __restrict__ vals,
                           float* __restrict__ out) {
    const int b  = blockIdx.x >> 2;   // 64
    const int dt = blockIdx.x & 3;    // 4 d-tiles of 256
    const int d  = dt * 256 + threadIdx.x;
    __shared__ float la[256];
    float acc = 0.f;
    for (int sc = 0; sc < 1024; sc += 256) {
        __syncthreads();
        la[threadIdx.x] = attn[(sc + threadIdx.x) * 64 + b];
        __syncthreads();
#pragma unroll 8
        for (int j = 0; j < 256; ++j)
            acc += la[j] * vals[(size_t)(sc + j) * 1024 + d];
    }
    out[b * 1024 + d] = acc;
}

extern "C" void kernel_launch(void* const* d_in, const int* in_sizes, int n_in,
                              void* d_out, int out_size, void* d_ws, size_t ws_size,
                              hipStream_t stream) {
    const float* q  = (const float*)d_in[0];
    const float* k  = (const float*)d_in[1];
    const float* v  = (const float*)d_in[2];
    const float* wq = (const float*)d_in[3];
    const float* wk = (const float*)d_in[4];
    const float* wv = (const float*)d_in[5];
    float* out = (float*)d_out;

    const size_t abf_elems = (size_t)R_DIM * KP;   // 134,217,728 bf16 = 256 MiB
    const size_t bbf_elems = (size_t)H_DIM * KP;   //   2,097,152 bf16 =   4 MiB
    const size_t need = abf_elems * 2 + bbf_elems * 2 + (size_t)R_DIM * 4 * 2;
    const bool pre = (ws_size >= need);

    unsigned short* Abf = (unsigned short*)d_ws;
    unsigned short* Bbf = nullptr;
    float* scores;
    if (pre) {
        Bbf    = Abf + abf_elems;
        scores = (float*)(Bbf + bbf_elems);
    } else {
        scores = (float*)d_ws;       // fallback: only 512 KiB of ws used
    }
    float* attn = scores + R_DIM;

    hipMemsetAsync(scores, 0, R_DIM * sizeof(float), stream);

    if (pre) {
        cvt_qk_kernel<<<65536, 256, 0, stream>>>(q, k, Abf);
        cvt_w_kernel<<<1024, 256, 0, stream>>>(wq, wk, Bbf);
        score_gemm<true><<<4096, 256, 0, stream>>>(q, k, wq, wk, Abf, Bbf, wv, scores);
    } else {
        score_gemm<false><<<4096, 256, 0, stream>>>(q, k, wq, wk, nullptr, nullptr, wv, scores);
    }
    softmax_kernel<<<64, 256, 0, stream>>>(scores, attn);
    out_kernel<<<256, 256, 0, stream>>>(attn, v, out);
}